// Round 7
// baseline (358.596 us; speedup 1.0000x reference)
//
#include <hip/hip_runtime.h>
#include <hip/hip_cooperative_groups.h>

namespace cg = cooperative_groups;

// DistanceNorm: (B, L, M) f32, B=16, L=2048, M=1024 — single cooperative kernel.
//  Phase 1: each block owns 32 rows of one batch; f32 column sums -> f64
//           (s0, s1) pair per block -> ws  (identical tree to validated R3).
//  grid.sync()
//  Phase 2: 64-lane butterfly over the 64 pairs of this block's batch ->
//           scale -> indices in registers -> gather the SAME 32 rows ->
//           nontemporal float4 stores.
// Memory-bound: 134 MB HBM read + 134 MB L3-resident re-read + 134 MB write.

typedef float f32x4 __attribute__((ext_vector_type(4)));

constexpr int L    = 2048;
constexpr int M    = 1024;
constexpr int BPB  = 64;           // blocks per batch element
constexpr int ROWS = L / BPB;      // 32 rows per block

__global__ __launch_bounds__(256, 4) void distnorm_fused(
    const float* __restrict__ d, float* __restrict__ out,
    double* __restrict__ sums) {
    const int blk = blockIdx.x;            // b * BPB + c
    const int b   = blk / BPB;
    const int c   = blk % BPB;
    const int t   = threadIdx.x;
    const int m0  = t * 4;

    const size_t row0 = ((size_t)b * L + (size_t)c * ROWS) * M;

    // ---- Phase 1: column-sum my 32 rows (f32), fold to f64 (s0, s1) ----
    {
        const float* base = d + row0 + m0;
        float a0 = 0.f, a1 = 0.f, a2 = 0.f, a3 = 0.f;
#pragma unroll 8
        for (int l = 0; l < ROWS; ++l) {
            f32x4 v = *reinterpret_cast<const f32x4*>(base + (size_t)l * M);
            a0 += v.x; a1 += v.y; a2 += v.z; a3 += v.w;
        }
        double s0 = (double)a0 + (double)a1 + (double)a2 + (double)a3;
        double s1 = (double)a0 * (double)(m0 + 0) + (double)a1 * (double)(m0 + 1) +
                    (double)a2 * (double)(m0 + 2) + (double)a3 * (double)(m0 + 3);

#pragma unroll
        for (int off = 32; off > 0; off >>= 1) {
            s0 += __shfl_down(s0, off);
            s1 += __shfl_down(s1, off);
        }
        __shared__ double ls0[4], ls1[4];
        const int wave = t >> 6, lane = t & 63;
        if (lane == 0) { ls0[wave] = s0; ls1[wave] = s1; }
        __syncthreads();
        if (t == 0) {
            sums[2 * (size_t)blk + 0] = ls0[0] + ls0[1] + ls0[2] + ls0[3];
            sums[2 * (size_t)blk + 1] = ls1[0] + ls1[1] + ls1[2] + ls1[3];
        }
    }

    cg::this_grid().sync();

    // ---- Phase 2: reduce 64 pairs of my batch -> scale (identical tree) ----
    __shared__ float sscale;
    if (t < 64) {
        double s0 = sums[(size_t)b * (2 * BPB) + 2 * t + 0];
        double s1 = sums[(size_t)b * (2 * BPB) + 2 * t + 1];
#pragma unroll
        for (int off = 32; off > 0; off >>= 1) {
            s0 += __shfl_down(s0, off);
            s1 += __shfl_down(s1, off);
        }
        if (t == 0) sscale = (float)((s1 / s0) / (0.5 * (double)M));
    }
    __syncthreads();
    const float sc = sscale;

    // mirror JAX: idx = clip(int32(f32(scale) * f32(m)), 0, M-1)
    const int i0 = min(max((int)(sc * (float)(m0 + 0)), 0), M - 1);
    const int i1 = min(max((int)(sc * (float)(m0 + 1)), 0), M - 1);
    const int i2 = min(max((int)(sc * (float)(m0 + 2)), 0), M - 1);
    const int i3 = min(max((int)(sc * (float)(m0 + 3)), 0), M - 1);

    // ---- gather the same 32 rows; out written once -> nontemporal ----
    const float* rowbase = d   + row0;
    float*       outbase = out + row0;
#pragma unroll 4
    for (int r = 0; r < ROWS; ++r) {
        const float* row = rowbase + (size_t)r * M;
        f32x4 v;
        v.x = row[i0];
        v.y = row[i1];
        v.z = row[i2];
        v.w = row[i3];
        __builtin_nontemporal_store(v,
            reinterpret_cast<f32x4*>(outbase + (size_t)r * M + m0));
    }
}

extern "C" void kernel_launch(void* const* d_in, const int* in_sizes, int n_in,
                              void* d_out, int out_size, void* d_ws, size_t ws_size,
                              hipStream_t stream) {
    const float* d = (const float*)d_in[0];
    float* out = (float*)d_out;
    const int n = in_sizes[0];
    const int B = n / (L * M);             // 16 for the bench shape

    double* sums = (double*)d_ws;          // B * BPB * 2 doubles = 16 KB

    void* args[] = {(void*)&d, (void*)&out, (void*)&sums};
    hipLaunchCooperativeKernel((const void*)distnorm_fused,
                               dim3(B * BPB), dim3(256), args, 0, stream);
}

// Round 8
// 249.132 us; speedup vs baseline: 1.4394x; 1.4394x over previous
//
#include <hip/hip_runtime.h>

// DistanceNorm: (B, L, M) f32, B=16, L=2048, M=1024 — two kernels (validated
// R3 structure; cooperative fusion regressed 2.4x: pinned 16 waves/CU was
// latency-bound on the scattered gather).
//  Kernel A: per-(b, L-chunk) f32 column sums over 32 rows -> f64 (s0, s1)
//            pair per chunk -> ws (16 KB). Bitwise-identical to R3.
//  Kernel B: per-block butterfly over the 64 chunk pairs -> scale -> indices;
//            gather 8 rows/block at 4096 blocks. NEW: unaligned f32x4
//            fast path when i3 == i0+3 (true for ~255/256 threads at sc<1),
//            scalar fallback otherwise. Nontemporal stores for out.
// Memory-bound: 134 MB HBM read + 134 MB L3-resident re-read + 134 MB write.

typedef float f32x4 __attribute__((ext_vector_type(4)));

constexpr int L    = 2048;
constexpr int M    = 1024;
constexpr int LCH  = 64;           // chunks per batch in kernel A
constexpr int ROWS = L / LCH;      // 32 rows per chunk
constexpr int RPB  = 8;            // rows per gather block
constexpr int GPB  = L / RPB;      // 256 gather blocks per batch

__global__ __launch_bounds__(256) void colsum_reduce(
    const float* __restrict__ d, double* __restrict__ sums) {
    const int blk = blockIdx.x;            // b * LCH + lch
    const int b   = blk / LCH;
    const int lch = blk % LCH;
    const int t   = threadIdx.x;
    const int m0  = t * 4;

    const float* base = d + ((size_t)b * L + (size_t)lch * ROWS) * M + m0;
    float a0 = 0.f, a1 = 0.f, a2 = 0.f, a3 = 0.f;
#pragma unroll 8
    for (int l = 0; l < ROWS; ++l) {
        f32x4 v = *reinterpret_cast<const f32x4*>(base + (size_t)l * M);
        a0 += v.x; a1 += v.y; a2 += v.z; a3 += v.w;
    }
    double s0 = (double)a0 + (double)a1 + (double)a2 + (double)a3;
    double s1 = (double)a0 * (double)(m0 + 0) + (double)a1 * (double)(m0 + 1) +
                (double)a2 * (double)(m0 + 2) + (double)a3 * (double)(m0 + 3);

#pragma unroll
    for (int off = 32; off > 0; off >>= 1) {
        s0 += __shfl_down(s0, off);
        s1 += __shfl_down(s1, off);
    }
    __shared__ double ls0[4], ls1[4];
    const int wave = t >> 6, lane = t & 63;
    if (lane == 0) { ls0[wave] = s0; ls1[wave] = s1; }
    __syncthreads();
    if (t == 0) {
        sums[2 * (size_t)blk + 0] = ls0[0] + ls0[1] + ls0[2] + ls0[3];
        sums[2 * (size_t)blk + 1] = ls1[0] + ls1[1] + ls1[2] + ls1[3];
    }
}

__global__ __launch_bounds__(256) void gather_rows(
    const float* __restrict__ d, const double* __restrict__ sums,
    float* __restrict__ out) {
    const int blk = blockIdx.x;            // b * GPB + g
    const int b   = blk / GPB;
    const int l0  = (blk % GPB) * RPB;
    const int t   = threadIdx.x;

    // deterministic per-block scale: identical butterfly in every block
    __shared__ float sscale;
    if (t < 64) {
        double s0 = sums[(size_t)b * (2 * LCH) + 2 * t + 0];
        double s1 = sums[(size_t)b * (2 * LCH) + 2 * t + 1];
#pragma unroll
        for (int off = 32; off > 0; off >>= 1) {
            s0 += __shfl_down(s0, off);
            s1 += __shfl_down(s1, off);
        }
        if (t == 0) sscale = (float)((s1 / s0) / (0.5 * (double)M));
    }
    __syncthreads();
    const float sc = sscale;

    // mirror JAX: idx = clip(int32(f32(scale) * f32(m)), 0, M-1)
    const int m0 = t * 4;
    const int i0 = min(max((int)(sc * (float)(m0 + 0)), 0), M - 1);
    const int i1 = min(max((int)(sc * (float)(m0 + 1)), 0), M - 1);
    const int i2 = min(max((int)(sc * (float)(m0 + 2)), 0), M - 1);
    const int i3 = min(max((int)(sc * (float)(m0 + 3)), 0), M - 1);
    const bool fast = (i1 == i0 + 1) & (i2 == i0 + 2) & (i3 == i0 + 3);

    const float* rowbase = d   + ((size_t)b * L + l0) * M;
    float*       outbase = out + ((size_t)b * L + l0) * M;
#pragma unroll
    for (int r = 0; r < RPB; ++r) {
        const float* row = rowbase + (size_t)r * M;
        f32x4 v;
        if (fast) {
            // contiguous indices: one dword-aligned dwordx4 (16B/lane,
            // ~16B lane stride -> coalesced ~1KB/wave)
            __builtin_memcpy(&v, row + i0, sizeof(f32x4));
        } else {
            v.x = row[i0];
            v.y = row[i1];
            v.z = row[i2];
            v.w = row[i3];
        }
        __builtin_nontemporal_store(v,
            reinterpret_cast<f32x4*>(outbase + (size_t)r * M + m0));
    }
}

extern "C" void kernel_launch(void* const* d_in, const int* in_sizes, int n_in,
                              void* d_out, int out_size, void* d_ws, size_t ws_size,
                              hipStream_t stream) {
    const float* d = (const float*)d_in[0];
    float* out = (float*)d_out;
    const int n = in_sizes[0];
    const int B = n / (L * M);             // 16 for the bench shape

    double* sums = (double*)d_ws;          // B * LCH * 2 doubles = 16 KB

    colsum_reduce<<<B * LCH, 256, 0, stream>>>(d, sums);
    gather_rows<<<B * GPB, 256, 0, stream>>>(d, sums, out);
}

// Round 10
// 248.100 us; speedup vs baseline: 1.4454x; 1.0042x over previous
//
#include <hip/hip_runtime.h>

// DistanceNorm: (B, L, M) f32, B=16, L=2048, M=1024 — two kernels.
//  Kernel A: per-(b, L-chunk) f32 column sums over 16 rows -> f64 (s0, s1)
//            pair per chunk -> ws (32 KB). LCH=128 => 2048 blocks = 8/CU =
//            32 waves/CU (100% occupancy for the HBM stream; was 50% at 1024).
//  Kernel B: per-block butterfly over the 128 chunk pairs (lanes pre-add two
//            pairs; deterministic, identical in all blocks) -> scale ->
//            indices; gather 8 rows/block, f32x4 fast path (sc<1 => indices
//            contiguous for ~255/256 threads), nontemporal stores.
// Memory-bound: 134 MB HBM read + 134 MB L3-resident re-read + 134 MB write.
// R7 lesson: cooperative fusion pins occupancy during gather -> 2.4x regress.
// R8 lesson: fast-path gather neutral -> gather not load-instruction-bound.

typedef float f32x4 __attribute__((ext_vector_type(4)));

constexpr int L    = 2048;
constexpr int M    = 1024;
constexpr int LCH  = 128;          // chunks per batch in kernel A
constexpr int ROWS = L / LCH;      // 16 rows per chunk
constexpr int RPB  = 8;            // rows per gather block
constexpr int GPB  = L / RPB;      // 256 gather blocks per batch

__global__ __launch_bounds__(256) void colsum_reduce(
    const float* __restrict__ d, double* __restrict__ sums) {
    const int blk = blockIdx.x;            // b * LCH + lch
    const int b   = blk / LCH;
    const int lch = blk % LCH;
    const int t   = threadIdx.x;
    const int m0  = t * 4;

    const float* base = d + ((size_t)b * L + (size_t)lch * ROWS) * M + m0;
    float a0 = 0.f, a1 = 0.f, a2 = 0.f, a3 = 0.f;
#pragma unroll 8
    for (int l = 0; l < ROWS; ++l) {
        f32x4 v = *reinterpret_cast<const f32x4*>(base + (size_t)l * M);
        a0 += v.x; a1 += v.y; a2 += v.z; a3 += v.w;
    }
    double s0 = (double)a0 + (double)a1 + (double)a2 + (double)a3;
    double s1 = (double)a0 * (double)(m0 + 0) + (double)a1 * (double)(m0 + 1) +
                (double)a2 * (double)(m0 + 2) + (double)a3 * (double)(m0 + 3);

#pragma unroll
    for (int off = 32; off > 0; off >>= 1) {
        s0 += __shfl_down(s0, off);
        s1 += __shfl_down(s1, off);
    }
    __shared__ double ls0[4], ls1[4];
    const int wave = t >> 6, lane = t & 63;
    if (lane == 0) { ls0[wave] = s0; ls1[wave] = s1; }
    __syncthreads();
    if (t == 0) {
        sums[2 * (size_t)blk + 0] = ls0[0] + ls0[1] + ls0[2] + ls0[3];
        sums[2 * (size_t)blk + 1] = ls1[0] + ls1[1] + ls1[2] + ls1[3];
    }
}

__global__ __launch_bounds__(256) void gather_rows(
    const float* __restrict__ d, const double* __restrict__ sums,
    float* __restrict__ out) {
    const int blk = blockIdx.x;            // b * GPB + g
    const int b   = blk / GPB;
    const int l0  = (blk % GPB) * RPB;
    const int t   = threadIdx.x;

    // deterministic per-block scale: identical fold+butterfly in every block
    __shared__ float sscale;
    if (t < 64) {
        const double* sb = sums + (size_t)b * (2 * LCH);
        double s0 = sb[2 * t + 0] + sb[2 * (t + 64) + 0];
        double s1 = sb[2 * t + 1] + sb[2 * (t + 64) + 1];
#pragma unroll
        for (int off = 32; off > 0; off >>= 1) {
            s0 += __shfl_down(s0, off);
            s1 += __shfl_down(s1, off);
        }
        if (t == 0) sscale = (float)((s1 / s0) / (0.5 * (double)M));
    }
    __syncthreads();
    const float sc = sscale;

    // mirror JAX: idx = clip(int32(f32(scale) * f32(m)), 0, M-1)
    const int m0 = t * 4;
    const int i0 = min(max((int)(sc * (float)(m0 + 0)), 0), M - 1);
    const int i1 = min(max((int)(sc * (float)(m0 + 1)), 0), M - 1);
    const int i2 = min(max((int)(sc * (float)(m0 + 2)), 0), M - 1);
    const int i3 = min(max((int)(sc * (float)(m0 + 3)), 0), M - 1);
    const bool fast = (i1 == i0 + 1) & (i2 == i0 + 2) & (i3 == i0 + 3);

    const float* rowbase = d   + ((size_t)b * L + l0) * M;
    float*       outbase = out + ((size_t)b * L + l0) * M;
#pragma unroll
    for (int r = 0; r < RPB; ++r) {
        const float* row = rowbase + (size_t)r * M;
        f32x4 v;
        if (fast) {
            __builtin_memcpy(&v, row + i0, sizeof(f32x4));
        } else {
            v.x = row[i0];
            v.y = row[i1];
            v.z = row[i2];
            v.w = row[i3];
        }
        __builtin_nontemporal_store(v,
            reinterpret_cast<f32x4*>(outbase + (size_t)r * M + m0));
    }
}

extern "C" void kernel_launch(void* const* d_in, const int* in_sizes, int n_in,
                              void* d_out, int out_size, void* d_ws, size_t ws_size,
                              hipStream_t stream) {
    const float* d = (const float*)d_in[0];
    float* out = (float*)d_out;
    const int n = in_sizes[0];
    const int B = n / (L * M);             // 16 for the bench shape

    double* sums = (double*)d_ws;          // B * LCH * 2 doubles = 32 KB

    colsum_reduce<<<B * LCH, 256, 0, stream>>>(d, sums);
    gather_rows<<<B * GPB, 256, 0, stream>>>(d, sums, out);
}